// Round 7
// baseline (107.178 us; speedup 1.0000x reference)
//
#include <hip/hip_runtime.h>
#include <hip/hip_bf16.h>
#include <hip/hip_fp16.h>
#include <math.h>

#define N_NODES 50000
#define N_EDGES 800000
#define IN_DIM 128
#define OUT_DIM 64

typedef __attribute__((ext_vector_type(8))) short bf16x8;
typedef __attribute__((ext_vector_type(4))) float f32x4;

static __device__ __forceinline__ ushort f2bf(float f) {
  uint u = __float_as_uint(f);
  uint r = (u + 0x7fffu + ((u >> 16) & 1u)) >> 16;  // RNE
  return (ushort)r;
}
static __device__ __forceinline__ float bf2f(ushort h) {
  return __uint_as_float(((uint)h) << 16);
}

#define N4 (N_NODES / 4)            // 12500
#define SCAN_NB ((N4 + 255) / 256)  // 49
#define GEMM_NB ((N_NODES + 63) / 64)         // 782 tiles
#define E4 (N_EDGES / 4)                      // 200000 int4-groups
#define K4_T (N_EDGES / 8)                    // 100000

// ---------------------------------------------------------------------------
// K0: zero deg
// ---------------------------------------------------------------------------
__global__ __launch_bounds__(256) void k0_zero(int* __restrict__ deg) {
  int i4 = blockIdx.x * 256 + threadIdx.x;
  if (i4 < N4) ((int4*)deg)[i4] = make_int4(0, 0, 0, 0);
}

// ---------------------------------------------------------------------------
// K12: GEMM + rank side-duty, atomics LAST.
// vmcnt is FIFO (m135): slow ops must be the YOUNGEST in flight or they
// block every later s_waitcnt. Round-6 issued atomics first and serialized
// the whole block. Now: load dst4 early (fast), full GEMM, then 4 atomics +
// rank store at the end — only the rank store waits on them.
//   GEMM: h = x@W, x split hi/lo bf16, W hi-only; h fp16 + a1/a2 epilogue.
// ---------------------------------------------------------------------------
__global__ __launch_bounds__(256) void k12_fused(
    const float* __restrict__ x, const float* __restrict__ W,
    const float* __restrict__ att, const int* __restrict__ dstp,
    __half* __restrict__ h, float* __restrict__ a1, float* __restrict__ a2,
    int* __restrict__ deg, int* __restrict__ rank) {
  __shared__ __align__(16) ushort Ah[64 * 128];
  __shared__ __align__(16) ushort Al[64 * 128];
  __shared__ __align__(16) ushort Bh[64 * 128];

  int tid = threadIdx.x;
  int row0 = blockIdx.x * 64;

  // ---- side duty, part 1: ONLY the dst load (fast, non-blocking) ----
  int e4 = blockIdx.x * 256 + tid;
  bool has_e = e4 < E4;
  int4 d4 = make_int4(0, 0, 0, 0);
  if (has_e) d4 = ((const int4*)dstp)[e4];

  // ---- stage x tile: 64x128 f32 = 2048 float4; 8/thread; hi/lo bf16 ----
#pragma unroll
  for (int it = 0; it < 8; ++it) {
    int i4 = it * 256 + tid;
    int row = i4 >> 5;
    int kq = i4 & 31;
    int grow = row0 + row;
    if (grow > N_NODES - 1) grow = N_NODES - 1;
    float4 v = ((const float4*)x)[(size_t)grow * 32 + kq];
    ushort4 hi, lo;
    hi.x = f2bf(v.x); lo.x = f2bf(v.x - bf2f(hi.x));
    hi.y = f2bf(v.y); lo.y = f2bf(v.y - bf2f(hi.y));
    hi.z = f2bf(v.z); lo.z = f2bf(v.z - bf2f(hi.z));
    hi.w = f2bf(v.w); lo.w = f2bf(v.w - bf2f(hi.w));
    int idx = (row * 128 + kq * 4) ^ ((row & 7) << 3);
    *(ushort4*)&Ah[idx] = hi;
    *(ushort4*)&Al[idx] = lo;
  }

  // ---- stage W transposed (hi only): BT[c][k] ----
  {
    int c = tid & 63, kq = tid >> 6;
#pragma unroll
    for (int jj = 0; jj < 4; ++jj) {
      int kb = kq * 32 + jj * 8;
      uint4 ph;
      uint hp[8];
#pragma unroll
      for (int q = 0; q < 8; ++q) hp[q] = f2bf(W[(size_t)(kb + q) * OUT_DIM + c]);
      ph.x = hp[0] | (hp[1] << 16); ph.y = hp[2] | (hp[3] << 16);
      ph.z = hp[4] | (hp[5] << 16); ph.w = hp[6] | (hp[7] << 16);
      int idx = (c * 128 + kb) ^ ((c & 7) << 3);
      *(uint4*)&Bh[idx] = ph;
    }
  }
  __syncthreads();

  int w = tid >> 6, l = tid & 63;
  int ml = l & 15, kg = l >> 4;

  f32x4 acc[4];
#pragma unroll
  for (int nt = 0; nt < 4; ++nt) acc[nt] = (f32x4){0.f, 0.f, 0.f, 0.f};

#pragma unroll
  for (int ks = 0; ks < 4; ++ks) {
    int arow = w * 16 + ml;
    int aidx = (arow * 128 + ks * 32 + kg * 8) ^ ((arow & 7) << 3);
    bf16x8 a_h = *(const bf16x8*)&Ah[aidx];
    bf16x8 a_l = *(const bf16x8*)&Al[aidx];
#pragma unroll
    for (int nt = 0; nt < 4; ++nt) {
      int brow = nt * 16 + ml;
      int bidx = (brow * 128 + ks * 32 + kg * 8) ^ ((brow & 7) << 3);
      bf16x8 b_h = *(const bf16x8*)&Bh[bidx];
      acc[nt] = __builtin_amdgcn_mfma_f32_16x16x32_bf16(a_h, b_h, acc[nt], 0, 0, 0);
      acc[nt] = __builtin_amdgcn_mfma_f32_16x16x32_bf16(a_l, b_h, acc[nt], 0, 0, 0);
    }
  }

  // ---- epilogue: C/D layout col=lane&15, row=(lane>>4)*4+reg [m89] ----
  float t1[4], t2[4];
#pragma unroll
  for (int nt = 0; nt < 4; ++nt) {
    t1[nt] = att[nt * 16 + ml];
    t2[nt] = att[OUT_DIM + nt * 16 + ml];
  }
#pragma unroll
  for (int r = 0; r < 4; ++r) {
    int drow = kg * 4 + r;
    int grow = row0 + w * 16 + drow;
    bool ok = grow < N_NODES;
    float p1 = 0.f, p2 = 0.f;
#pragma unroll
    for (int nt = 0; nt < 4; ++nt) {
      float d = acc[nt][r];
      if (ok) h[(size_t)grow * OUT_DIM + nt * 16 + ml] = __float2half(d);
      p1 = fmaf(d, t1[nt], p1);
      p2 = fmaf(d, t2[nt], p2);
    }
#pragma unroll
    for (int o = 1; o <= 8; o <<= 1) {
      p1 += __shfl_xor(p1, o, 64);
      p2 += __shfl_xor(p2, o, 64);
    }
    if (ml == 0 && ok) { a1[grow] = p1; a2[grow] = p2; }
  }

  // ---- side duty, part 2: atomics LAST (youngest in flight) ----
  if (has_e) {
    int4 r4;
    r4.x = atomicAdd(&deg[d4.x], 1);
    r4.y = atomicAdd(&deg[d4.y], 1);
    r4.z = atomicAdd(&deg[d4.z], 1);
    r4.w = atomicAdd(&deg[d4.w], 1);
    ((int4*)rank)[e4] = r4;
  }
}

// ---------------------------------------------------------------------------
// K3a: per-block scan of deg (int4); K3c: bsum scan + add + pack {off,a2}
// ---------------------------------------------------------------------------
__global__ __launch_bounds__(256) void k3a_scan(const int* __restrict__ deg,
                                                int* __restrict__ off,
                                                int* __restrict__ bsum) {
  __shared__ int sw[4];
  int tid = threadIdx.x, lane = tid & 63, wid = tid >> 6;
  int i4 = blockIdx.x * 256 + tid;
  int4 v = make_int4(0, 0, 0, 0);
  if (i4 < N4) v = ((const int4*)deg)[i4];
  int local = v.x + v.y + v.z + v.w;
  int incl = local;
#pragma unroll
  for (int o = 1; o < 64; o <<= 1) {
    int t = __shfl_up(incl, o, 64);
    if (lane >= o) incl += t;
  }
  if (lane == 63) sw[wid] = incl;
  __syncthreads();
  if (tid == 0) {
    int c = 0;
#pragma unroll
    for (int ww = 0; ww < 4; ++ww) { int t = sw[ww]; sw[ww] = c; c += t; }
    bsum[blockIdx.x] = c;
  }
  __syncthreads();
  int excl = incl - local + sw[wid];
  int4 o;
  o.x = excl; o.y = o.x + v.x; o.z = o.y + v.y; o.w = o.z + v.z;
  if (i4 < N4) ((int4*)off)[i4] = o;
}

__global__ __launch_bounds__(256) void k3c_add(int* __restrict__ off,
                                               const int* __restrict__ bsum,
                                               const float* __restrict__ a2,
                                               int2* __restrict__ oa2) {
  __shared__ int sb[64];
  int tid = threadIdx.x;
  if (tid < 64) {
    int v = (tid < SCAN_NB) ? bsum[tid] : 0;
    int incl = v;
#pragma unroll
    for (int o = 1; o < 64; o <<= 1) {
      int t = __shfl_up(incl, o, 64);
      if (tid >= o) incl += t;
    }
    sb[tid] = incl - v;  // exclusive block prefix
  }
  __syncthreads();
  int i4 = blockIdx.x * 256 + tid;
  if (i4 == 0) off[N_NODES] = N_EDGES;
  if (i4 >= N4) return;
  int add = sb[blockIdx.x];
  int4 v = ((const int4*)off)[i4];
  v.x += add; v.y += add; v.z += add; v.w += add;
  ((int4*)off)[i4] = v;
  float4 a = ((const float4*)a2)[i4];
  int4 p0 = make_int4(v.x, __float_as_int(a.x), v.y, __float_as_int(a.y));
  int4 p1 = make_int4(v.z, __float_as_int(a.z), v.w, __float_as_int(a.w));
  ((int4*)oa2)[i4 * 2] = p0;
  ((int4*)oa2)[i4 * 2 + 1] = p1;
}

// ---------------------------------------------------------------------------
// K4: atomic-free scatter, 8 edges/thread
// sedge[off[d]+rank] = {src, exp(leaky(a1+a2))}
// ---------------------------------------------------------------------------
__global__ __launch_bounds__(256) void k4_scatter(
    const int* __restrict__ src, const int* __restrict__ dstp,
    const int* __restrict__ rank,
    const float* __restrict__ a1, const int2* __restrict__ oa2,
    int2* __restrict__ sedge) {
  int t = blockIdx.x * 256 + threadIdx.x;
  if (t >= K4_T) return;
  int4 s0 = ((const int4*)src)[t * 2],  s1 = ((const int4*)src)[t * 2 + 1];
  int4 d0 = ((const int4*)dstp)[t * 2], d1 = ((const int4*)dstp)[t * 2 + 1];
  int4 r0 = ((const int4*)rank)[t * 2], r1 = ((const int4*)rank)[t * 2 + 1];
  float A[8];
  A[0] = a1[s0.x]; A[1] = a1[s0.y]; A[2] = a1[s0.z]; A[3] = a1[s0.w];
  A[4] = a1[s1.x]; A[5] = a1[s1.y]; A[6] = a1[s1.z]; A[7] = a1[s1.w];
  int2 O[8];
  O[0] = oa2[d0.x]; O[1] = oa2[d0.y]; O[2] = oa2[d0.z]; O[3] = oa2[d0.w];
  O[4] = oa2[d1.x]; O[5] = oa2[d1.y]; O[6] = oa2[d1.z]; O[7] = oa2[d1.w];
  int S[8] = {s0.x, s0.y, s0.z, s0.w, s1.x, s1.y, s1.z, s1.w};
  int R[8] = {r0.x, r0.y, r0.z, r0.w, r1.x, r1.y, r1.z, r1.w};
#pragma unroll
  for (int q = 0; q < 8; ++q) {
    float e = A[q] + __int_as_float(O[q].y);
    e = e > 0.f ? e : 0.2f * e;  // leaky_relu 0.2
    // logits O(1): exp w/o max pass (softmax shift-invariant)
    sedge[O[q].x + R[q]] = make_int2(S[q], __float_as_int(__expf(e)));
  }
}

// ---------------------------------------------------------------------------
// K5: per-node weighted aggregation + ELU. 8 lanes/node (uint4/lane),
// 8 nodes/wave, 8-edge unroll -> 64 row-gathers in flight per wave.
// ---------------------------------------------------------------------------
__global__ __launch_bounds__(256) void k5_agg(
    const int* __restrict__ off, const int2* __restrict__ sedge,
    const __half* __restrict__ h, float* __restrict__ out) {
  int tid = threadIdx.x;
  int g = tid >> 3, gl = tid & 7;
  int n = blockIdx.x * 32 + g;
  if (n >= N_NODES) return;
  int b = off[n], e = off[n + 1];

  float sum = 0.f;
  float a0 = 0.f, a1_ = 0.f, a2_ = 0.f, a3 = 0.f;
  float a4 = 0.f, a5 = 0.f, a6 = 0.f, a7 = 0.f;
  const __half* __restrict__ hb = h;

#define K5_ACC(rr, ww)                                                        \
  {                                                                           \
    float2 f;                                                                 \
    f = __half22float2(__builtin_bit_cast(__half2, rr.x));                    \
    a0 = fmaf(ww, f.x, a0); a1_ = fmaf(ww, f.y, a1_);                         \
    f = __half22float2(__builtin_bit_cast(__half2, rr.y));                    \
    a2_ = fmaf(ww, f.x, a2_); a3 = fmaf(ww, f.y, a3);                         \
    f = __half22float2(__builtin_bit_cast(__half2, rr.z));                    \
    a4 = fmaf(ww, f.x, a4); a5 = fmaf(ww, f.y, a5);                           \
    f = __half22float2(__builtin_bit_cast(__half2, rr.w));                    \
    a6 = fmaf(ww, f.x, a6); a7 = fmaf(ww, f.y, a7);                           \
  }

  int j = b;
  for (; j + 7 < e; j += 8) {
    int2 s0 = sedge[j + 0], s1 = sedge[j + 1], s2 = sedge[j + 2], s3 = sedge[j + 3];
    int2 s4 = sedge[j + 4], s5 = sedge[j + 5], s6 = sedge[j + 6], s7 = sedge[j + 7];
    uint4 r0 = ((const uint4*)(hb + (size_t)s0.x * OUT_DIM))[gl];
    uint4 r1 = ((const uint4*)(hb + (size_t)s1.x * OUT_DIM))[gl];
    uint4 r2 = ((const uint4*)(hb + (size_t)s2.x * OUT_DIM))[gl];
    uint4 r3 = ((const uint4*)(hb + (size_t)s3.x * OUT_DIM))[gl];
    uint4 r4 = ((const uint4*)(hb + (size_t)s4.x * OUT_DIM))[gl];
    uint4 r5 = ((const uint4*)(hb + (size_t)s5.x * OUT_DIM))[gl];
    uint4 r6 = ((const uint4*)(hb + (size_t)s6.x * OUT_DIM))[gl];
    uint4 r7 = ((const uint4*)(hb + (size_t)s7.x * OUT_DIM))[gl];
    float w0 = __int_as_float(s0.y), w1 = __int_as_float(s1.y);
    float w2 = __int_as_float(s2.y), w3 = __int_as_float(s3.y);
    float w4 = __int_as_float(s4.y), w5 = __int_as_float(s5.y);
    float w6 = __int_as_float(s6.y), w7 = __int_as_float(s7.y);
    sum += ((w0 + w1) + (w2 + w3)) + ((w4 + w5) + (w6 + w7));
    K5_ACC(r0, w0); K5_ACC(r1, w1); K5_ACC(r2, w2); K5_ACC(r3, w3);
    K5_ACC(r4, w4); K5_ACC(r5, w5); K5_ACC(r6, w6); K5_ACC(r7, w7);
  }
  for (; j + 3 < e; j += 4) {
    int2 s0 = sedge[j + 0], s1 = sedge[j + 1], s2 = sedge[j + 2], s3 = sedge[j + 3];
    uint4 r0 = ((const uint4*)(hb + (size_t)s0.x * OUT_DIM))[gl];
    uint4 r1 = ((const uint4*)(hb + (size_t)s1.x * OUT_DIM))[gl];
    uint4 r2 = ((const uint4*)(hb + (size_t)s2.x * OUT_DIM))[gl];
    uint4 r3 = ((const uint4*)(hb + (size_t)s3.x * OUT_DIM))[gl];
    float w0 = __int_as_float(s0.y), w1 = __int_as_float(s1.y);
    float w2 = __int_as_float(s2.y), w3 = __int_as_float(s3.y);
    sum += (w0 + w1) + (w2 + w3);
    K5_ACC(r0, w0); K5_ACC(r1, w1); K5_ACC(r2, w2); K5_ACC(r3, w3);
  }
  for (; j < e; ++j) {
    int2 s0 = sedge[j];
    uint4 r0 = ((const uint4*)(hb + (size_t)s0.x * OUT_DIM))[gl];
    float w0 = __int_as_float(s0.y);
    sum += w0;
    K5_ACC(r0, w0);
  }

  float inv = (e > b) ? 1.f / sum : 0.f;
  a0 *= inv; a1_ *= inv; a2_ *= inv; a3 *= inv;
  a4 *= inv; a5 *= inv; a6 *= inv; a7 *= inv;
  float4 o0, o1;
  o0.x = a0 > 0.f ? a0 : (__expf(a0) - 1.f);
  o0.y = a1_ > 0.f ? a1_ : (__expf(a1_) - 1.f);
  o0.z = a2_ > 0.f ? a2_ : (__expf(a2_) - 1.f);
  o0.w = a3 > 0.f ? a3 : (__expf(a3) - 1.f);
  o1.x = a4 > 0.f ? a4 : (__expf(a4) - 1.f);
  o1.y = a5 > 0.f ? a5 : (__expf(a5) - 1.f);
  o1.z = a6 > 0.f ? a6 : (__expf(a6) - 1.f);
  o1.w = a7 > 0.f ? a7 : (__expf(a7) - 1.f);
  float4* ob = (float4*)(out + (size_t)n * OUT_DIM);
  ob[gl * 2] = o0;
  ob[gl * 2 + 1] = o1;
}

// ---------------------------------------------------------------------------
extern "C" void kernel_launch(void* const* d_in, const int* in_sizes, int n_in,
                              void* d_out, int out_size, void* d_ws, size_t ws_size,
                              hipStream_t stream) {
  const float* x   = (const float*)d_in[0];
  const int*   ei  = (const int*)d_in[1];   // [2, E]
  const float* W   = (const float*)d_in[2];
  const float* att = (const float*)d_in[3];
  float* out = (float*)d_out;

  char* p = (char*)d_ws;
  __half* h  = (__half*)p;  p += (size_t)N_NODES * OUT_DIM * sizeof(__half);  // 6.4 MB
  float* a1  = (float*)p;   p += (size_t)N_NODES * sizeof(float);
  float* a2  = (float*)p;   p += (size_t)N_NODES * sizeof(float);
  int*   deg = (int*)p;     p += (size_t)N_NODES * sizeof(int);
  int*   off = (int*)p;     p += (size_t)(N_NODES + 4) * sizeof(int);
  int2*  oa2 = (int2*)p;    p += (size_t)N_NODES * sizeof(int2);
  int*   rank = (int*)p;    p += (size_t)N_EDGES * sizeof(int);               // 3.2 MB
  int2*  sedge = (int2*)p;  p += (size_t)N_EDGES * sizeof(int2);              // 6.4 MB
  int*   bsum = (int*)p;    p += 64 * sizeof(int);

  const int* src  = ei;
  const int* dstp = ei + N_EDGES;

  k0_zero<<<SCAN_NB, 256, 0, stream>>>(deg);
  k12_fused<<<GEMM_NB, 256, 0, stream>>>(x, W, att, dstp, h, a1, a2, deg, rank);
  k3a_scan<<<SCAN_NB, 256, 0, stream>>>(deg, off, bsum);
  k3c_add<<<SCAN_NB, 256, 0, stream>>>(off, bsum, a2, oa2);
  k4_scatter<<<(K4_T + 255) / 256, 256, 0, stream>>>(src, dstp, rank, a1, oa2, sedge);
  k5_agg<<<(N_NODES + 31) / 32, 256, 0, stream>>>(off, sedge, h, out);
}

// Round 8
// 103.577 us; speedup vs baseline: 1.0348x; 1.0348x over previous
//
#include <hip/hip_runtime.h>
#include <hip/hip_bf16.h>
#include <hip/hip_fp16.h>
#include <math.h>

#define N_NODES 50000
#define N_EDGES 800000
#define IN_DIM 128
#define OUT_DIM 64

typedef __attribute__((ext_vector_type(8))) short bf16x8;
typedef __attribute__((ext_vector_type(4))) float f32x4;

static __device__ __forceinline__ ushort f2bf(float f) {
  uint u = __float_as_uint(f);
  uint r = (u + 0x7fffu + ((u >> 16) & 1u)) >> 16;  // RNE
  return (ushort)r;
}
static __device__ __forceinline__ float bf2f(ushort h) {
  return __uint_as_float(((uint)h) << 16);
}

#define N4 (N_NODES / 4)            // 12500
#define SCAN_NB ((N4 + 255) / 256)  // 49
#define GEMM_NB ((N_NODES + 63) / 64)         // 782 tiles
#define K2_T (N_EDGES / 8)                    // 100000
#define K4_T (N_EDGES / 8)                    // 100000

// ---------------------------------------------------------------------------
// K0: zero deg + transpose-convert W (fp32 [128][64]) -> WTbf (bf16 [64][128])
// ---------------------------------------------------------------------------
__global__ __launch_bounds__(256) void k0_prep(const float* __restrict__ W,
                                               int* __restrict__ deg,
                                               ushort* __restrict__ WTbf) {
  int t = blockIdx.x * 256 + threadIdx.x;
  if (t < N4) ((int4*)deg)[t] = make_int4(0, 0, 0, 0);
  if (t < IN_DIM * OUT_DIM) {
    int k = t >> 6, c = t & 63;           // coalesced read of W[k][c]
    WTbf[c * IN_DIM + k] = f2bf(W[t]);
  }
}

// ---------------------------------------------------------------------------
// K1: h = x @ W, ZERO-LDS MFMA GEMM.
// Lesson r5-r7: 48KB-LDS tiles -> 3 blocks/CU -> ONE cohort -> kernel time =
// one block's serial latency chain. Now: A-fragments loaded per-lane straight
// from x (2xfloat4 per K-step, in-register hi/lo bf16 split: 2-term
// (x_hi+x_lo)*W_hi, err ~W-rounding ~6e-4); B-fragments read from the 16KB
// WTbf table (L1/L2-resident). No staging, no syncthreads, no bank conflicts;
// occupancy VGPR-bound; 24 independent loads/lane in flight.
//   epilogue: h fp16 store + fused a1/a2 row-reductions (C/D layout m89).
// ---------------------------------------------------------------------------
__global__ __launch_bounds__(256) void k1_mfma(
    const float* __restrict__ x, const ushort* __restrict__ WTbf,
    const float* __restrict__ att,
    __half* __restrict__ h, float* __restrict__ a1, float* __restrict__ a2) {
  int tid = threadIdx.x;
  int w = tid >> 6, l = tid & 63;
  int ml = l & 15, kg = l >> 4;
  int row0 = blockIdx.x * 64;

  int arow = row0 + w * 16 + ml;
  if (arow > N_NODES - 1) arow = N_NODES - 1;
  const float* __restrict__ xr = x + (size_t)arow * IN_DIM + kg * 8;

  // B fragments: 16 x 16B loads from 16KB table (cache-hot)
  bf16x8 b[4][4];
#pragma unroll
  for (int nt = 0; nt < 4; ++nt) {
    const ushort* wc = WTbf + (nt * 16 + ml) * IN_DIM + kg * 8;
#pragma unroll
    for (int ks = 0; ks < 4; ++ks)
      b[nt][ks] = *(const bf16x8*)(wc + ks * 32);
  }

  // A fragments: 8 x float4 from x, split hi/lo bf16 in-register
  bf16x8 a_h[4], a_l[4];
#pragma unroll
  for (int ks = 0; ks < 4; ++ks) {
    float4 v0 = *(const float4*)(xr + ks * 32);
    float4 v1 = *(const float4*)(xr + ks * 32 + 4);
    float vv[8] = {v0.x, v0.y, v0.z, v0.w, v1.x, v1.y, v1.z, v1.w};
    ushort hh[8], ll[8];
#pragma unroll
    for (int q = 0; q < 8; ++q) {
      hh[q] = f2bf(vv[q]);
      ll[q] = f2bf(vv[q] - bf2f(hh[q]));
    }
    a_h[ks] = (bf16x8){(short)hh[0], (short)hh[1], (short)hh[2], (short)hh[3],
                       (short)hh[4], (short)hh[5], (short)hh[6], (short)hh[7]};
    a_l[ks] = (bf16x8){(short)ll[0], (short)ll[1], (short)ll[2], (short)ll[3],
                       (short)ll[4], (short)ll[5], (short)ll[6], (short)ll[7]};
  }

  f32x4 acc[4];
#pragma unroll
  for (int nt = 0; nt < 4; ++nt) acc[nt] = (f32x4){0.f, 0.f, 0.f, 0.f};

#pragma unroll
  for (int ks = 0; ks < 4; ++ks) {
#pragma unroll
    for (int nt = 0; nt < 4; ++nt) {
      acc[nt] = __builtin_amdgcn_mfma_f32_16x16x32_bf16(a_h[ks], b[nt][ks], acc[nt], 0, 0, 0);
      acc[nt] = __builtin_amdgcn_mfma_f32_16x16x32_bf16(a_l[ks], b[nt][ks], acc[nt], 0, 0, 0);
    }
  }

  // epilogue: C/D layout col=lane&15, row=(lane>>4)*4+reg  [m89]
  float t1[4], t2[4];
#pragma unroll
  for (int nt = 0; nt < 4; ++nt) {
    t1[nt] = att[nt * 16 + ml];
    t2[nt] = att[OUT_DIM + nt * 16 + ml];
  }
#pragma unroll
  for (int r = 0; r < 4; ++r) {
    int drow = kg * 4 + r;
    int grow = row0 + w * 16 + drow;
    bool ok = grow < N_NODES;
    float p1 = 0.f, p2 = 0.f;
#pragma unroll
    for (int nt = 0; nt < 4; ++nt) {
      float d = acc[nt][r];
      if (ok) h[(size_t)grow * OUT_DIM + nt * 16 + ml] = __float2half(d);
      p1 = fmaf(d, t1[nt], p1);
      p2 = fmaf(d, t2[nt], p2);
    }
#pragma unroll
    for (int o = 1; o <= 8; o <<= 1) {
      p1 += __shfl_xor(p1, o, 64);
      p2 += __shfl_xor(p2, o, 64);
    }
    if (ml == 0 && ok) { a1[grow] = p1; a2[grow] = p2; }
  }
}

// ---------------------------------------------------------------------------
// K2: histogram + rank in ONE atomic, standalone (full occupancy, no LDS).
// 8 edges/thread -> 8 independent atomics in flight.
// ---------------------------------------------------------------------------
__global__ __launch_bounds__(256) void k2_rank(const int* __restrict__ dstp,
                                               int* __restrict__ deg,
                                               int* __restrict__ rank) {
  int t = blockIdx.x * 256 + threadIdx.x;
  if (t >= K2_T) return;
  int4 d0 = ((const int4*)dstp)[t * 2];
  int4 d1 = ((const int4*)dstp)[t * 2 + 1];
  int4 r0, r1;
  r0.x = atomicAdd(&deg[d0.x], 1);
  r0.y = atomicAdd(&deg[d0.y], 1);
  r0.z = atomicAdd(&deg[d0.z], 1);
  r0.w = atomicAdd(&deg[d0.w], 1);
  r1.x = atomicAdd(&deg[d1.x], 1);
  r1.y = atomicAdd(&deg[d1.y], 1);
  r1.z = atomicAdd(&deg[d1.z], 1);
  r1.w = atomicAdd(&deg[d1.w], 1);
  ((int4*)rank)[t * 2] = r0;
  ((int4*)rank)[t * 2 + 1] = r1;
}

// ---------------------------------------------------------------------------
// K3a: per-block scan of deg (int4); K3c: bsum scan + add + pack {off,a2}
// ---------------------------------------------------------------------------
__global__ __launch_bounds__(256) void k3a_scan(const int* __restrict__ deg,
                                                int* __restrict__ off,
                                                int* __restrict__ bsum) {
  __shared__ int sw[4];
  int tid = threadIdx.x, lane = tid & 63, wid = tid >> 6;
  int i4 = blockIdx.x * 256 + tid;
  int4 v = make_int4(0, 0, 0, 0);
  if (i4 < N4) v = ((const int4*)deg)[i4];
  int local = v.x + v.y + v.z + v.w;
  int incl = local;
#pragma unroll
  for (int o = 1; o < 64; o <<= 1) {
    int t = __shfl_up(incl, o, 64);
    if (lane >= o) incl += t;
  }
  if (lane == 63) sw[wid] = incl;
  __syncthreads();
  if (tid == 0) {
    int c = 0;
#pragma unroll
    for (int ww = 0; ww < 4; ++ww) { int t = sw[ww]; sw[ww] = c; c += t; }
    bsum[blockIdx.x] = c;
  }
  __syncthreads();
  int excl = incl - local + sw[wid];
  int4 o;
  o.x = excl; o.y = o.x + v.x; o.z = o.y + v.y; o.w = o.z + v.z;
  if (i4 < N4) ((int4*)off)[i4] = o;
}

__global__ __launch_bounds__(256) void k3c_add(int* __restrict__ off,
                                               const int* __restrict__ bsum,
                                               const float* __restrict__ a2,
                                               int2* __restrict__ oa2) {
  __shared__ int sb[64];
  int tid = threadIdx.x;
  if (tid < 64) {
    int v = (tid < SCAN_NB) ? bsum[tid] : 0;
    int incl = v;
#pragma unroll
    for (int o = 1; o < 64; o <<= 1) {
      int t = __shfl_up(incl, o, 64);
      if (tid >= o) incl += t;
    }
    sb[tid] = incl - v;  // exclusive block prefix
  }
  __syncthreads();
  int i4 = blockIdx.x * 256 + tid;
  if (i4 == 0) off[N_NODES] = N_EDGES;
  if (i4 >= N4) return;
  int add = sb[blockIdx.x];
  int4 v = ((const int4*)off)[i4];
  v.x += add; v.y += add; v.z += add; v.w += add;
  ((int4*)off)[i4] = v;
  float4 a = ((const float4*)a2)[i4];
  int4 p0 = make_int4(v.x, __float_as_int(a.x), v.y, __float_as_int(a.y));
  int4 p1 = make_int4(v.z, __float_as_int(a.z), v.w, __float_as_int(a.w));
  ((int4*)oa2)[i4 * 2] = p0;
  ((int4*)oa2)[i4 * 2 + 1] = p1;
}

// ---------------------------------------------------------------------------
// K4: atomic-free scatter, 8 edges/thread
// sedge[off[d]+rank] = {src, exp(leaky(a1+a2))}
// ---------------------------------------------------------------------------
__global__ __launch_bounds__(256) void k4_scatter(
    const int* __restrict__ src, const int* __restrict__ dstp,
    const int* __restrict__ rank,
    const float* __restrict__ a1, const int2* __restrict__ oa2,
    int2* __restrict__ sedge) {
  int t = blockIdx.x * 256 + threadIdx.x;
  if (t >= K4_T) return;
  int4 s0 = ((const int4*)src)[t * 2],  s1 = ((const int4*)src)[t * 2 + 1];
  int4 d0 = ((const int4*)dstp)[t * 2], d1 = ((const int4*)dstp)[t * 2 + 1];
  int4 r0 = ((const int4*)rank)[t * 2], r1 = ((const int4*)rank)[t * 2 + 1];
  float A[8];
  A[0] = a1[s0.x]; A[1] = a1[s0.y]; A[2] = a1[s0.z]; A[3] = a1[s0.w];
  A[4] = a1[s1.x]; A[5] = a1[s1.y]; A[6] = a1[s1.z]; A[7] = a1[s1.w];
  int2 O[8];
  O[0] = oa2[d0.x]; O[1] = oa2[d0.y]; O[2] = oa2[d0.z]; O[3] = oa2[d0.w];
  O[4] = oa2[d1.x]; O[5] = oa2[d1.y]; O[6] = oa2[d1.z]; O[7] = oa2[d1.w];
  int S[8] = {s0.x, s0.y, s0.z, s0.w, s1.x, s1.y, s1.z, s1.w};
  int R[8] = {r0.x, r0.y, r0.z, r0.w, r1.x, r1.y, r1.z, r1.w};
#pragma unroll
  for (int q = 0; q < 8; ++q) {
    float e = A[q] + __int_as_float(O[q].y);
    e = e > 0.f ? e : 0.2f * e;  // leaky_relu 0.2
    // logits O(1): exp w/o max pass (softmax shift-invariant)
    sedge[O[q].x + R[q]] = make_int2(S[q], __float_as_int(__expf(e)));
  }
}

// ---------------------------------------------------------------------------
// K5: per-node weighted aggregation + ELU. 8 lanes/node (uint4/lane),
// 8 nodes/wave, 8-edge unroll -> 64 row-gathers in flight per wave.
// ---------------------------------------------------------------------------
__global__ __launch_bounds__(256) void k5_agg(
    const int* __restrict__ off, const int2* __restrict__ sedge,
    const __half* __restrict__ h, float* __restrict__ out) {
  int tid = threadIdx.x;
  int g = tid >> 3, gl = tid & 7;
  int n = blockIdx.x * 32 + g;
  if (n >= N_NODES) return;
  int b = off[n], e = off[n + 1];

  float sum = 0.f;
  float a0 = 0.f, a1_ = 0.f, a2_ = 0.f, a3 = 0.f;
  float a4 = 0.f, a5 = 0.f, a6 = 0.f, a7 = 0.f;
  const __half* __restrict__ hb = h;

#define K5_ACC(rr, ww)                                                        \
  {                                                                           \
    float2 f;                                                                 \
    f = __half22float2(__builtin_bit_cast(__half2, rr.x));                    \
    a0 = fmaf(ww, f.x, a0); a1_ = fmaf(ww, f.y, a1_);                         \
    f = __half22float2(__builtin_bit_cast(__half2, rr.y));                    \
    a2_ = fmaf(ww, f.x, a2_); a3 = fmaf(ww, f.y, a3);                         \
    f = __half22float2(__builtin_bit_cast(__half2, rr.z));                    \
    a4 = fmaf(ww, f.x, a4); a5 = fmaf(ww, f.y, a5);                           \
    f = __half22float2(__builtin_bit_cast(__half2, rr.w));                    \
    a6 = fmaf(ww, f.x, a6); a7 = fmaf(ww, f.y, a7);                           \
  }

  int j = b;
  for (; j + 7 < e; j += 8) {
    int2 s0 = sedge[j + 0], s1 = sedge[j + 1], s2 = sedge[j + 2], s3 = sedge[j + 3];
    int2 s4 = sedge[j + 4], s5 = sedge[j + 5], s6 = sedge[j + 6], s7 = sedge[j + 7];
    uint4 r0 = ((const uint4*)(hb + (size_t)s0.x * OUT_DIM))[gl];
    uint4 r1 = ((const uint4*)(hb + (size_t)s1.x * OUT_DIM))[gl];
    uint4 r2 = ((const uint4*)(hb + (size_t)s2.x * OUT_DIM))[gl];
    uint4 r3 = ((const uint4*)(hb + (size_t)s3.x * OUT_DIM))[gl];
    uint4 r4 = ((const uint4*)(hb + (size_t)s4.x * OUT_DIM))[gl];
    uint4 r5 = ((const uint4*)(hb + (size_t)s5.x * OUT_DIM))[gl];
    uint4 r6 = ((const uint4*)(hb + (size_t)s6.x * OUT_DIM))[gl];
    uint4 r7 = ((const uint4*)(hb + (size_t)s7.x * OUT_DIM))[gl];
    float w0 = __int_as_float(s0.y), w1 = __int_as_float(s1.y);
    float w2 = __int_as_float(s2.y), w3 = __int_as_float(s3.y);
    float w4 = __int_as_float(s4.y), w5 = __int_as_float(s5.y);
    float w6 = __int_as_float(s6.y), w7 = __int_as_float(s7.y);
    sum += ((w0 + w1) + (w2 + w3)) + ((w4 + w5) + (w6 + w7));
    K5_ACC(r0, w0); K5_ACC(r1, w1); K5_ACC(r2, w2); K5_ACC(r3, w3);
    K5_ACC(r4, w4); K5_ACC(r5, w5); K5_ACC(r6, w6); K5_ACC(r7, w7);
  }
  for (; j + 3 < e; j += 4) {
    int2 s0 = sedge[j + 0], s1 = sedge[j + 1], s2 = sedge[j + 2], s3 = sedge[j + 3];
    uint4 r0 = ((const uint4*)(hb + (size_t)s0.x * OUT_DIM))[gl];
    uint4 r1 = ((const uint4*)(hb + (size_t)s1.x * OUT_DIM))[gl];
    uint4 r2 = ((const uint4*)(hb + (size_t)s2.x * OUT_DIM))[gl];
    uint4 r3 = ((const uint4*)(hb + (size_t)s3.x * OUT_DIM))[gl];
    float w0 = __int_as_float(s0.y), w1 = __int_as_float(s1.y);
    float w2 = __int_as_float(s2.y), w3 = __int_as_float(s3.y);
    sum += (w0 + w1) + (w2 + w3);
    K5_ACC(r0, w0); K5_ACC(r1, w1); K5_ACC(r2, w2); K5_ACC(r3, w3);
  }
  for (; j < e; ++j) {
    int2 s0 = sedge[j];
    uint4 r0 = ((const uint4*)(hb + (size_t)s0.x * OUT_DIM))[gl];
    float w0 = __int_as_float(s0.y);
    sum += w0;
    K5_ACC(r0, w0);
  }

  float inv = (e > b) ? 1.f / sum : 0.f;
  a0 *= inv; a1_ *= inv; a2_ *= inv; a3 *= inv;
  a4 *= inv; a5 *= inv; a6 *= inv; a7 *= inv;
  float4 o0, o1;
  o0.x = a0 > 0.f ? a0 : (__expf(a0) - 1.f);
  o0.y = a1_ > 0.f ? a1_ : (__expf(a1_) - 1.f);
  o0.z = a2_ > 0.f ? a2_ : (__expf(a2_) - 1.f);
  o0.w = a3 > 0.f ? a3 : (__expf(a3) - 1.f);
  o1.x = a4 > 0.f ? a4 : (__expf(a4) - 1.f);
  o1.y = a5 > 0.f ? a5 : (__expf(a5) - 1.f);
  o1.z = a6 > 0.f ? a6 : (__expf(a6) - 1.f);
  o1.w = a7 > 0.f ? a7 : (__expf(a7) - 1.f);
  float4* ob = (float4*)(out + (size_t)n * OUT_DIM);
  ob[gl * 2] = o0;
  ob[gl * 2 + 1] = o1;
}

// ---------------------------------------------------------------------------
extern "C" void kernel_launch(void* const* d_in, const int* in_sizes, int n_in,
                              void* d_out, int out_size, void* d_ws, size_t ws_size,
                              hipStream_t stream) {
  const float* x   = (const float*)d_in[0];
  const int*   ei  = (const int*)d_in[1];   // [2, E]
  const float* W   = (const float*)d_in[2];
  const float* att = (const float*)d_in[3];
  float* out = (float*)d_out;

  char* p = (char*)d_ws;
  __half* h  = (__half*)p;  p += (size_t)N_NODES * OUT_DIM * sizeof(__half);  // 6.4 MB
  float* a1  = (float*)p;   p += (size_t)N_NODES * sizeof(float);
  float* a2  = (float*)p;   p += (size_t)N_NODES * sizeof(float);
  int*   deg = (int*)p;     p += (size_t)N_NODES * sizeof(int);
  int*   off = (int*)p;     p += (size_t)(N_NODES + 4) * sizeof(int);
  int2*  oa2 = (int2*)p;    p += (size_t)N_NODES * sizeof(int2);
  int*   rank = (int*)p;    p += (size_t)N_EDGES * sizeof(int);               // 3.2 MB
  int2*  sedge = (int2*)p;  p += (size_t)N_EDGES * sizeof(int2);              // 6.4 MB
  int*   bsum = (int*)p;    p += 64 * sizeof(int);
  ushort* WTbf = (ushort*)p; p += (size_t)OUT_DIM * IN_DIM * sizeof(ushort);  // 16 KB

  const int* src  = ei;
  const int* dstp = ei + N_EDGES;

  k0_prep<<<SCAN_NB, 256, 0, stream>>>(W, deg, WTbf);
  k2_rank<<<(K2_T + 255) / 256, 256, 0, stream>>>(dstp, deg, rank);
  k1_mfma<<<GEMM_NB, 256, 0, stream>>>(x, WTbf, att, h, a1, a2);
  k3a_scan<<<SCAN_NB, 256, 0, stream>>>(deg, off, bsum);
  k3c_add<<<SCAN_NB, 256, 0, stream>>>(off, bsum, a2, oa2);
  k4_scatter<<<(K4_T + 255) / 256, 256, 0, stream>>>(src, dstp, rank, a1, oa2, sedge);
  k5_agg<<<(N_NODES + 31) / 32, 256, 0, stream>>>(off, sedge, h, out);
}

// Round 9
// 98.386 us; speedup vs baseline: 1.0894x; 1.0528x over previous
//
#include <hip/hip_runtime.h>
#include <hip/hip_bf16.h>
#include <hip/hip_fp16.h>
#include <math.h>

#define N_NODES 50000
#define N_EDGES 800000
#define IN_DIM 128
#define OUT_DIM 64

typedef __attribute__((ext_vector_type(8))) short bf16x8;
typedef __attribute__((ext_vector_type(4))) float f32x4;

static __device__ __forceinline__ ushort f2bf(float f) {
  uint u = __float_as_uint(f);
  uint r = (u + 0x7fffu + ((u >> 16) & 1u)) >> 16;  // RNE
  return (ushort)r;
}
static __device__ __forceinline__ float bf2f(ushort h) {
  return __uint_as_float(((uint)h) << 16);
}

#define N4 (N_NODES / 4)            // 12500
#define SCAN_NB ((N4 + 255) / 256)  // 49
#define GEMM_NB ((N_NODES + 63) / 64)         // 782 tiles
#define K2_T (N_EDGES / 8)                    // 100000
#define K4_T (N_EDGES / 8)                    // 100000

// ---------------------------------------------------------------------------
// K0: zero deg + pack W into MFMA-fragment order:
// WTfrag[((nt*4+ks)*64 + lane)*8 + j] = bf16(W[k][c]),
//   c = nt*16 + (lane&15), k = ks*32 + (lane>>4)*8 + j.
// k1's B-load becomes wave-uniform base + lane*16B -> coalesced, L1-hot.
// ---------------------------------------------------------------------------
__global__ __launch_bounds__(256) void k0_prep(const float* __restrict__ W,
                                               int* __restrict__ deg,
                                               ushort* __restrict__ WTfrag) {
  int t = blockIdx.x * 256 + threadIdx.x;
  if (t < N4) ((int4*)deg)[t] = make_int4(0, 0, 0, 0);
  if (t < IN_DIM * OUT_DIM) {
    int j = t & 7, l = (t >> 3) & 63, ks = (t >> 9) & 3, nt = (t >> 11) & 3;
    int c = nt * 16 + (l & 15);
    int k = ks * 32 + ((l >> 4) << 3) + j;
    WTfrag[t] = f2bf(W[(size_t)k * OUT_DIM + c]);
  }
}

// ---------------------------------------------------------------------------
// K1: h = x @ W. A staged in LDS (32KB, hi/lo bf16 -> 5 blocks/CU,
// 20 waves/CU), B straight from the 16KB WTfrag table (coalesced, L1).
// Lessons: r8 proved per-lane x loads can't coalesce (fragment layout);
// r5-7 proved 48KB LDS -> 3 blocks/CU -> single-cohort serialization.
// This keeps the coalesced stage but cuts LDS, W-chain and barrier cost.
//   2-term split: (x_hi + x_lo) * W_hi; err ~ W-rounding ~6e-4.
//   epilogue: h fp16 store + fused a1/a2 row-reductions (C/D layout m89).
// ---------------------------------------------------------------------------
__global__ __launch_bounds__(256) void k1_mfma(
    const float* __restrict__ x, const ushort* __restrict__ WTfrag,
    const float* __restrict__ att,
    __half* __restrict__ h, float* __restrict__ a1, float* __restrict__ a2) {
  __shared__ __align__(16) ushort Ah[64 * 128];
  __shared__ __align__(16) ushort Al[64 * 128];

  int tid = threadIdx.x;
  int row0 = blockIdx.x * 64;

  // stage x tile: 64x128 f32 = 2048 float4; 8/thread; hi/lo bf16; coalesced
#pragma unroll
  for (int it = 0; it < 8; ++it) {
    int i4 = it * 256 + tid;
    int row = i4 >> 5;
    int kq = i4 & 31;
    int grow = row0 + row;
    if (grow > N_NODES - 1) grow = N_NODES - 1;
    float4 v = ((const float4*)x)[(size_t)grow * 32 + kq];
    ushort4 hi, lo;
    hi.x = f2bf(v.x); lo.x = f2bf(v.x - bf2f(hi.x));
    hi.y = f2bf(v.y); lo.y = f2bf(v.y - bf2f(hi.y));
    hi.z = f2bf(v.z); lo.z = f2bf(v.z - bf2f(hi.z));
    hi.w = f2bf(v.w); lo.w = f2bf(v.w - bf2f(hi.w));
    int idx = (row * 128 + kq * 4) ^ ((row & 7) << 3);
    *(ushort4*)&Ah[idx] = hi;
    *(ushort4*)&Al[idx] = lo;
  }
  __syncthreads();

  int w = tid >> 6, l = tid & 63;
  int ml = l & 15, kg = l >> 4;
  const bf16x8* __restrict__ Bf = (const bf16x8*)WTfrag;

  f32x4 acc[4];
#pragma unroll
  for (int nt = 0; nt < 4; ++nt) acc[nt] = (f32x4){0.f, 0.f, 0.f, 0.f};

#pragma unroll
  for (int ks = 0; ks < 4; ++ks) {
    int arow = w * 16 + ml;
    int aidx = (arow * 128 + ks * 32 + kg * 8) ^ ((arow & 7) << 3);
    bf16x8 a_h = *(const bf16x8*)&Ah[aidx];
    bf16x8 a_l = *(const bf16x8*)&Al[aidx];
#pragma unroll
    for (int nt = 0; nt < 4; ++nt) {
      bf16x8 b = Bf[(nt * 4 + ks) * 64 + l];  // coalesced 1KB/wave, L1-hot
      acc[nt] = __builtin_amdgcn_mfma_f32_16x16x32_bf16(a_h, b, acc[nt], 0, 0, 0);
      acc[nt] = __builtin_amdgcn_mfma_f32_16x16x32_bf16(a_l, b, acc[nt], 0, 0, 0);
    }
  }

  // epilogue: C/D layout col=lane&15, row=(lane>>4)*4+reg  [m89]
  float t1[4], t2[4];
#pragma unroll
  for (int nt = 0; nt < 4; ++nt) {
    t1[nt] = att[nt * 16 + ml];
    t2[nt] = att[OUT_DIM + nt * 16 + ml];
  }
#pragma unroll
  for (int r = 0; r < 4; ++r) {
    int drow = kg * 4 + r;
    int grow = row0 + w * 16 + drow;
    bool ok = grow < N_NODES;
    float p1 = 0.f, p2 = 0.f;
#pragma unroll
    for (int nt = 0; nt < 4; ++nt) {
      float d = acc[nt][r];
      if (ok) h[(size_t)grow * OUT_DIM + nt * 16 + ml] = __float2half(d);
      p1 = fmaf(d, t1[nt], p1);
      p2 = fmaf(d, t2[nt], p2);
    }
#pragma unroll
    for (int o = 1; o <= 8; o <<= 1) {
      p1 += __shfl_xor(p1, o, 64);
      p2 += __shfl_xor(p2, o, 64);
    }
    if (ml == 0 && ok) { a1[grow] = p1; a2[grow] = p2; }
  }
}

// ---------------------------------------------------------------------------
// K2: histogram + rank in ONE atomic, standalone (no LDS, full occupancy).
// ---------------------------------------------------------------------------
__global__ __launch_bounds__(256) void k2_rank(const int* __restrict__ dstp,
                                               int* __restrict__ deg,
                                               int* __restrict__ rank) {
  int t = blockIdx.x * 256 + threadIdx.x;
  if (t >= K2_T) return;
  int4 d0 = ((const int4*)dstp)[t * 2];
  int4 d1 = ((const int4*)dstp)[t * 2 + 1];
  int4 r0, r1;
  r0.x = atomicAdd(&deg[d0.x], 1);
  r0.y = atomicAdd(&deg[d0.y], 1);
  r0.z = atomicAdd(&deg[d0.z], 1);
  r0.w = atomicAdd(&deg[d0.w], 1);
  r1.x = atomicAdd(&deg[d1.x], 1);
  r1.y = atomicAdd(&deg[d1.y], 1);
  r1.z = atomicAdd(&deg[d1.z], 1);
  r1.w = atomicAdd(&deg[d1.w], 1);
  ((int4*)rank)[t * 2] = r0;
  ((int4*)rank)[t * 2 + 1] = r1;
}

// ---------------------------------------------------------------------------
// K3a: per-block scan of deg (int4); K3c: bsum scan + add + pack {off,a2}
// ---------------------------------------------------------------------------
__global__ __launch_bounds__(256) void k3a_scan(const int* __restrict__ deg,
                                                int* __restrict__ off,
                                                int* __restrict__ bsum) {
  __shared__ int sw[4];
  int tid = threadIdx.x, lane = tid & 63, wid = tid >> 6;
  int i4 = blockIdx.x * 256 + tid;
  int4 v = make_int4(0, 0, 0, 0);
  if (i4 < N4) v = ((const int4*)deg)[i4];
  int local = v.x + v.y + v.z + v.w;
  int incl = local;
#pragma unroll
  for (int o = 1; o < 64; o <<= 1) {
    int t = __shfl_up(incl, o, 64);
    if (lane >= o) incl += t;
  }
  if (lane == 63) sw[wid] = incl;
  __syncthreads();
  if (tid == 0) {
    int c = 0;
#pragma unroll
    for (int ww = 0; ww < 4; ++ww) { int t = sw[ww]; sw[ww] = c; c += t; }
    bsum[blockIdx.x] = c;
  }
  __syncthreads();
  int excl = incl - local + sw[wid];
  int4 o;
  o.x = excl; o.y = o.x + v.x; o.z = o.y + v.y; o.w = o.z + v.z;
  if (i4 < N4) ((int4*)off)[i4] = o;
}

__global__ __launch_bounds__(256) void k3c_add(int* __restrict__ off,
                                               const int* __restrict__ bsum,
                                               const float* __restrict__ a2,
                                               int2* __restrict__ oa2) {
  __shared__ int sb[64];
  int tid = threadIdx.x;
  if (tid < 64) {
    int v = (tid < SCAN_NB) ? bsum[tid] : 0;
    int incl = v;
#pragma unroll
    for (int o = 1; o < 64; o <<= 1) {
      int t = __shfl_up(incl, o, 64);
      if (tid >= o) incl += t;
    }
    sb[tid] = incl - v;  // exclusive block prefix
  }
  __syncthreads();
  int i4 = blockIdx.x * 256 + tid;
  if (i4 == 0) off[N_NODES] = N_EDGES;
  if (i4 >= N4) return;
  int add = sb[blockIdx.x];
  int4 v = ((const int4*)off)[i4];
  v.x += add; v.y += add; v.z += add; v.w += add;
  ((int4*)off)[i4] = v;
  float4 a = ((const float4*)a2)[i4];
  int4 p0 = make_int4(v.x, __float_as_int(a.x), v.y, __float_as_int(a.y));
  int4 p1 = make_int4(v.z, __float_as_int(a.z), v.w, __float_as_int(a.w));
  ((int4*)oa2)[i4 * 2] = p0;
  ((int4*)oa2)[i4 * 2 + 1] = p1;
}

// ---------------------------------------------------------------------------
// K4: atomic-free scatter, 8 edges/thread
// sedge[off[d]+rank] = {src, exp(leaky(a1+a2))}
// ---------------------------------------------------------------------------
__global__ __launch_bounds__(256) void k4_scatter(
    const int* __restrict__ src, const int* __restrict__ dstp,
    const int* __restrict__ rank,
    const float* __restrict__ a1, const int2* __restrict__ oa2,
    int2* __restrict__ sedge) {
  int t = blockIdx.x * 256 + threadIdx.x;
  if (t >= K4_T) return;
  int4 s0 = ((const int4*)src)[t * 2],  s1 = ((const int4*)src)[t * 2 + 1];
  int4 d0 = ((const int4*)dstp)[t * 2], d1 = ((const int4*)dstp)[t * 2 + 1];
  int4 r0 = ((const int4*)rank)[t * 2], r1 = ((const int4*)rank)[t * 2 + 1];
  float A[8];
  A[0] = a1[s0.x]; A[1] = a1[s0.y]; A[2] = a1[s0.z]; A[3] = a1[s0.w];
  A[4] = a1[s1.x]; A[5] = a1[s1.y]; A[6] = a1[s1.z]; A[7] = a1[s1.w];
  int2 O[8];
  O[0] = oa2[d0.x]; O[1] = oa2[d0.y]; O[2] = oa2[d0.z]; O[3] = oa2[d0.w];
  O[4] = oa2[d1.x]; O[5] = oa2[d1.y]; O[6] = oa2[d1.z]; O[7] = oa2[d1.w];
  int S[8] = {s0.x, s0.y, s0.z, s0.w, s1.x, s1.y, s1.z, s1.w};
  int R[8] = {r0.x, r0.y, r0.z, r0.w, r1.x, r1.y, r1.z, r1.w};
#pragma unroll
  for (int q = 0; q < 8; ++q) {
    float e = A[q] + __int_as_float(O[q].y);
    e = e > 0.f ? e : 0.2f * e;  // leaky_relu 0.2
    // logits O(1): exp w/o max pass (softmax shift-invariant)
    sedge[O[q].x + R[q]] = make_int2(S[q], __float_as_int(__expf(e)));
  }
}

// ---------------------------------------------------------------------------
// K5: per-node weighted aggregation + ELU. 8 lanes/node (uint4/lane),
// 8 nodes/wave, 8-edge unroll -> 64 row-gathers in flight per wave.
// ---------------------------------------------------------------------------
__global__ __launch_bounds__(256) void k5_agg(
    const int* __restrict__ off, const int2* __restrict__ sedge,
    const __half* __restrict__ h, float* __restrict__ out) {
  int tid = threadIdx.x;
  int g = tid >> 3, gl = tid & 7;
  int n = blockIdx.x * 32 + g;
  if (n >= N_NODES) return;
  int b = off[n], e = off[n + 1];

  float sum = 0.f;
  float a0 = 0.f, a1_ = 0.f, a2_ = 0.f, a3 = 0.f;
  float a4 = 0.f, a5 = 0.f, a6 = 0.f, a7 = 0.f;
  const __half* __restrict__ hb = h;

#define K5_ACC(rr, ww)                                                        \
  {                                                                           \
    float2 f;                                                                 \
    f = __half22float2(__builtin_bit_cast(__half2, rr.x));                    \
    a0 = fmaf(ww, f.x, a0); a1_ = fmaf(ww, f.y, a1_);                         \
    f = __half22float2(__builtin_bit_cast(__half2, rr.y));                    \
    a2_ = fmaf(ww, f.x, a2_); a3 = fmaf(ww, f.y, a3);                         \
    f = __half22float2(__builtin_bit_cast(__half2, rr.z));                    \
    a4 = fmaf(ww, f.x, a4); a5 = fmaf(ww, f.y, a5);                           \
    f = __half22float2(__builtin_bit_cast(__half2, rr.w));                    \
    a6 = fmaf(ww, f.x, a6); a7 = fmaf(ww, f.y, a7);                           \
  }

  int j = b;
  for (; j + 7 < e; j += 8) {
    int2 s0 = sedge[j + 0], s1 = sedge[j + 1], s2 = sedge[j + 2], s3 = sedge[j + 3];
    int2 s4 = sedge[j + 4], s5 = sedge[j + 5], s6 = sedge[j + 6], s7 = sedge[j + 7];
    uint4 r0 = ((const uint4*)(hb + (size_t)s0.x * OUT_DIM))[gl];
    uint4 r1 = ((const uint4*)(hb + (size_t)s1.x * OUT_DIM))[gl];
    uint4 r2 = ((const uint4*)(hb + (size_t)s2.x * OUT_DIM))[gl];
    uint4 r3 = ((const uint4*)(hb + (size_t)s3.x * OUT_DIM))[gl];
    uint4 r4 = ((const uint4*)(hb + (size_t)s4.x * OUT_DIM))[gl];
    uint4 r5 = ((const uint4*)(hb + (size_t)s5.x * OUT_DIM))[gl];
    uint4 r6 = ((const uint4*)(hb + (size_t)s6.x * OUT_DIM))[gl];
    uint4 r7 = ((const uint4*)(hb + (size_t)s7.x * OUT_DIM))[gl];
    float w0 = __int_as_float(s0.y), w1 = __int_as_float(s1.y);
    float w2 = __int_as_float(s2.y), w3 = __int_as_float(s3.y);
    float w4 = __int_as_float(s4.y), w5 = __int_as_float(s5.y);
    float w6 = __int_as_float(s6.y), w7 = __int_as_float(s7.y);
    sum += ((w0 + w1) + (w2 + w3)) + ((w4 + w5) + (w6 + w7));
    K5_ACC(r0, w0); K5_ACC(r1, w1); K5_ACC(r2, w2); K5_ACC(r3, w3);
    K5_ACC(r4, w4); K5_ACC(r5, w5); K5_ACC(r6, w6); K5_ACC(r7, w7);
  }
  for (; j + 3 < e; j += 4) {
    int2 s0 = sedge[j + 0], s1 = sedge[j + 1], s2 = sedge[j + 2], s3 = sedge[j + 3];
    uint4 r0 = ((const uint4*)(hb + (size_t)s0.x * OUT_DIM))[gl];
    uint4 r1 = ((const uint4*)(hb + (size_t)s1.x * OUT_DIM))[gl];
    uint4 r2 = ((const uint4*)(hb + (size_t)s2.x * OUT_DIM))[gl];
    uint4 r3 = ((const uint4*)(hb + (size_t)s3.x * OUT_DIM))[gl];
    float w0 = __int_as_float(s0.y), w1 = __int_as_float(s1.y);
    float w2 = __int_as_float(s2.y), w3 = __int_as_float(s3.y);
    sum += (w0 + w1) + (w2 + w3);
    K5_ACC(r0, w0); K5_ACC(r1, w1); K5_ACC(r2, w2); K5_ACC(r3, w3);
  }
  for (; j < e; ++j) {
    int2 s0 = sedge[j];
    uint4 r0 = ((const uint4*)(hb + (size_t)s0.x * OUT_DIM))[gl];
    float w0 = __int_as_float(s0.y);
    sum += w0;
    K5_ACC(r0, w0);
  }

  float inv = (e > b) ? 1.f / sum : 0.f;
  a0 *= inv; a1_ *= inv; a2_ *= inv; a3 *= inv;
  a4 *= inv; a5 *= inv; a6 *= inv; a7 *= inv;
  float4 o0, o1;
  o0.x = a0 > 0.f ? a0 : (__expf(a0) - 1.f);
  o0.y = a1_ > 0.f ? a1_ : (__expf(a1_) - 1.f);
  o0.z = a2_ > 0.f ? a2_ : (__expf(a2_) - 1.f);
  o0.w = a3 > 0.f ? a3 : (__expf(a3) - 1.f);
  o1.x = a4 > 0.f ? a4 : (__expf(a4) - 1.f);
  o1.y = a5 > 0.f ? a5 : (__expf(a5) - 1.f);
  o1.z = a6 > 0.f ? a6 : (__expf(a6) - 1.f);
  o1.w = a7 > 0.f ? a7 : (__expf(a7) - 1.f);
  float4* ob = (float4*)(out + (size_t)n * OUT_DIM);
  ob[gl * 2] = o0;
  ob[gl * 2 + 1] = o1;
}

// ---------------------------------------------------------------------------
extern "C" void kernel_launch(void* const* d_in, const int* in_sizes, int n_in,
                              void* d_out, int out_size, void* d_ws, size_t ws_size,
                              hipStream_t stream) {
  const float* x   = (const float*)d_in[0];
  const int*   ei  = (const int*)d_in[1];   // [2, E]
  const float* W   = (const float*)d_in[2];
  const float* att = (const float*)d_in[3];
  float* out = (float*)d_out;

  char* p = (char*)d_ws;
  __half* h  = (__half*)p;  p += (size_t)N_NODES * OUT_DIM * sizeof(__half);  // 6.4 MB
  float* a1  = (float*)p;   p += (size_t)N_NODES * sizeof(float);
  float* a2  = (float*)p;   p += (size_t)N_NODES * sizeof(float);
  int*   deg = (int*)p;     p += (size_t)N_NODES * sizeof(int);
  int*   off = (int*)p;     p += (size_t)(N_NODES + 4) * sizeof(int);
  int2*  oa2 = (int2*)p;    p += (size_t)N_NODES * sizeof(int2);
  int*   rank = (int*)p;    p += (size_t)N_EDGES * sizeof(int);               // 3.2 MB
  int2*  sedge = (int2*)p;  p += (size_t)N_EDGES * sizeof(int2);              // 6.4 MB
  int*   bsum = (int*)p;    p += 64 * sizeof(int);
  ushort* WTfrag = (ushort*)p; p += (size_t)OUT_DIM * IN_DIM * sizeof(ushort);

  const int* src  = ei;
  const int* dstp = ei + N_EDGES;

  k0_prep<<<SCAN_NB, 256, 0, stream>>>(W, deg, WTfrag);
  k2_rank<<<(K2_T + 255) / 256, 256, 0, stream>>>(dstp, deg, rank);
  k1_mfma<<<GEMM_NB, 256, 0, stream>>>(x, WTfrag, att, h, a1, a2);
  k3a_scan<<<SCAN_NB, 256, 0, stream>>>(deg, off, bsum);
  k3c_add<<<SCAN_NB, 256, 0, stream>>>(off, bsum, a2, oa2);
  k4_scatter<<<(K4_T + 255) / 256, 256, 0, stream>>>(src, dstp, rank, a1, oa2, sedge);
  k5_agg<<<(N_NODES + 31) / 32, 256, 0, stream>>>(off, sedge, h, out);
}